// Round 5
// baseline (613.401 us; speedup 1.0000x reference)
//
#include <hip/hip_runtime.h>
#include <hip/hip_fp16.h>
#include <cstdint>
#include <cstddef>

#define B_ 8
#define S_ 4096
#define D_ 1024
#define H_ 512
#define NBLK 1024

typedef __attribute__((ext_vector_type(8))) _Float16 half8;
typedef __attribute__((ext_vector_type(16))) float f16v;

union HU { int4 v; half8 h; };

__device__ inline unsigned short f2h(float f){
  _Float16 h = (_Float16)f;
  return __builtin_bit_cast(unsigned short, h);
}

#define AS1 __attribute__((address_space(1)))
#define AS3 __attribute__((address_space(3)))

// ---------- tiny init: grid-sync counters + first/last seeds ----------
__global__ void k_init(int* sc, int* fl){
  if (threadIdx.x == 0){
    sc[0] = 0; sc[1] = 0;
    fl[0] = 0x7FFFFFFF; fl[1] = -1; fl[2] = 0;
  }
}

// ---------- grid-wide sync (all NBLK blocks co-resident by construction) ----------
__device__ inline void gsync(int* c){
  __syncthreads();                 // drains each wave's vmem (compiler emits vmcnt(0))
  if (threadIdx.x == 0){
    __threadfence();               // release: wb L2 (device scope)
    __hip_atomic_fetch_add(c, 1, __ATOMIC_RELEASE, __HIP_MEMORY_SCOPE_AGENT);
    while (__hip_atomic_load(c, __ATOMIC_RELAXED, __HIP_MEMORY_SCOPE_AGENT) < NBLK)
      __builtin_amdgcn_s_sleep(32);
    __threadfence();               // acquire: inv L1/L2
  }
  __syncthreads();
}

union SMU {
  struct { unsigned short A[2][4096]; unsigned short B[2][4096]; } g;  // 32 KB
  struct { float tile[32][33]; int sc[256]; } p;
};

#define STAGE(kt_, nb_) do { int k0e = (kt_)*32; \
  char* abase = (char*)sm.g.A[nb_]; char* bbase = (char*)sm.g.B[nb_]; \
  _Pragma("unroll") for (int q=0;q<2;q++){ \
    __builtin_amdgcn_global_load_lds((const AS1 void*)(agp[q]+k0e), (AS3 void*)(abase+aldo[q]),16,0,0); \
    __builtin_amdgcn_global_load_lds((const AS1 void*)(bgp[q]+k0e), (AS3 void*)(bbase+bldo[q]),16,0,0); } \
} while(0)

// ---------- mega: pre (normdot+cast+W1T+prefix+zero) | GEMM | flags ----------
__global__ __launch_bounds__(256, 4) void k_mega(
    const float* __restrict__ X, const int* __restrict__ mask,
    const float* __restrict__ w1, const float* __restrict__ b1,
    const float* __restrict__ w2, const float* __restrict__ b2p,
    unsigned short* __restrict__ Xh, unsigned short* __restrict__ w1t,
    float* __restrict__ n2o, float* __restrict__ dto, float* __restrict__ logit,
    float* __restrict__ gsums, float* __restrict__ gcnt, int* __restrict__ cb,
    int* __restrict__ fl, int* __restrict__ sc, float* __restrict__ ob){
  __shared__ __align__(16) SMU sm;
  int bid = blockIdx.x, tid = threadIdx.x;
  int wave = tid>>6, lane = tid&63;

  // ---- phase 0a: normdot + cast for rows [bid*32, bid*32+32), 8 rows/wave ----
  {
    int g0 = bid*32 + wave*8;
    const float4* Xv = (const float4*)X;
    ushort4* Xhv = (ushort4*)Xh;
    float4 pv[4];
    if ((g0 & (S_-1)) != 0){
      size_t bb = (size_t)(g0-1)*256;
      #pragma unroll
      for (int q=0;q<4;q++) pv[q] = Xv[bb + q*64 + lane];
    } else {
      #pragma unroll
      for (int q=0;q<4;q++) pv[q] = make_float4(0.f,0.f,0.f,0.f);
    }
    for (int r=0;r<8;r++){
      int g = g0 + r;
      size_t bb = (size_t)g*256;
      float4 cv[4];
      #pragma unroll
      for (int q=0;q<4;q++) cv[q] = Xv[bb + q*64 + lane];
      float n2=0.f, dp=0.f;
      #pragma unroll
      for (int q=0;q<4;q++){
        n2 += cv[q].x*cv[q].x + cv[q].y*cv[q].y + cv[q].z*cv[q].z + cv[q].w*cv[q].w;
        dp += pv[q].x*cv[q].x + pv[q].y*cv[q].y + pv[q].z*cv[q].z + pv[q].w*cv[q].w;
      }
      #pragma unroll
      for (int q=0;q<4;q++){
        ushort4 u;
        u.x = f2h(cv[q].x); u.y = f2h(cv[q].y); u.z = f2h(cv[q].z); u.w = f2h(cv[q].w);
        Xhv[bb + q*64 + lane] = u;
      }
      #pragma unroll
      for (int off=32; off>0; off>>=1){
        n2 += __shfl_down(n2, off);
        dp += __shfl_down(dp, off);
      }
      if (lane==0){
        n2o[g] = n2;
        if ((g & (S_-1)) != 0) dto[g-1] = dp;
      }
      #pragma unroll
      for (int q=0;q<4;q++) pv[q] = cv[q];
    }
  }

  // ---- phase 0b: per-block role ----
  if (bid < 512){
    // W1^T f16 tile
    int n0 = (bid&15)*32, k0 = (bid>>4)*32;
    int tx = tid&31, ty = tid>>5;
    __syncthreads();
    #pragma unroll
    for (int i=0;i<4;i++) sm.p.tile[ty+8*i][tx] = w1[(size_t)(k0+ty+8*i)*H_ + n0+tx];
    __syncthreads();
    #pragma unroll
    for (int i=0;i<4;i++) w1t[(size_t)(n0+ty+8*i)*D_ + k0+tx] = f2h(sm.p.tile[tx][ty+8*i]);
  } else if (bid < 520){
    // mask prefix for batch row bid-512
    int bb = bid - 512;
    const int* mrow = mask + (size_t)bb*S_ + tid*16;
    int s = 0;
    #pragma unroll
    for (int i=0;i<16;i++) s += mrow[i];
    __syncthreads();
    sm.p.sc[tid] = s;
    __syncthreads();
    for (int off=1; off<256; off<<=1){
      int v = (tid>=off) ? sm.p.sc[tid-off] : 0;
      __syncthreads();
      sm.p.sc[tid] += v;
      __syncthreads();
    }
    if ((tid & 15) == 0) cb[bb*16 + (tid>>4)] = (tid==0) ? 0 : sm.p.sc[tid-1];
  } else if (bid < 552){
    ((float4*)logit)[(bid-520)*256 + tid] = make_float4(0.f,0.f,0.f,0.f);
  } else if (bid < 616){
    ((float4*)gsums)[(bid-552)*256 + tid] = make_float4(0.f,0.f,0.f,0.f);
  } else if (bid == 616){
    if (tid < 64) gcnt[tid] = 0.f;
  }

  gsync(sc + 0);

  // ---- phase 1: GEMM 128x128 tile (R4 structure verbatim) ----
  {
    int l31 = lane&31, h = lane>>5;
    int m0 = (bid>>2)*128, n0 = (bid&3)*128;
    int wm = (wave>>1)*64, wn = (wave&1)*64;
    f16v acc[2][2] = {};

    int srow = lane>>2;
    const unsigned short* agp[2]; const unsigned short* bgp[2];
    unsigned aldo[2], bldo[2];
    #pragma unroll
    for (int q=0;q<2;q++){
      int rb = wave*32 + q*16;
      int r  = rb + srow;
      int c  = (lane&3) ^ ((r>>1)&3);
      agp[q] = Xh  + (size_t)(m0 + r)*D_ + c*8;
      bgp[q] = w1t + (size_t)(n0 + r)*D_ + c*8;
      aldo[q] = rb*64;
      bldo[q] = rb*64;
    }

    unsigned aoff[2][2], boff[2][2];
    #pragma unroll
    for (int i=0;i<2;i++){
      int rm = wm + 32*i + l31;
      int rn = wn + 32*i + l31;
      #pragma unroll
      for (int kk=0;kk<2;kk++){
        int c = kk*2 + h;
        aoff[i][kk] = rm*64 + ((c ^ ((rm>>1)&3))<<4);
        boff[i][kk] = rn*64 + ((c ^ ((rn>>1)&3))<<4);
      }
    }

    float b1v[2], w2v[2];
    #pragma unroll
    for (int j=0;j<2;j++){
      int n = n0 + wn + 32*j + l31;
      b1v[j] = b1[n]; w2v[j] = w2[n];
    }

    STAGE(0, 0);
    for (int kt=0; kt<32; ++kt){
      __syncthreads();
      if (kt < 31) STAGE(kt+1, (kt+1)&1);
      const char* ab = (const char*)sm.g.A[kt&1];
      const char* bb = (const char*)sm.g.B[kt&1];
      #pragma unroll
      for (int kk=0;kk<2;kk++){
        HU a0, a1, b0, b1u;
        a0.v  = *(const int4*)(ab + aoff[0][kk]);
        a1.v  = *(const int4*)(ab + aoff[1][kk]);
        b0.v  = *(const int4*)(bb + boff[0][kk]);
        b1u.v = *(const int4*)(bb + boff[1][kk]);
        acc[0][0] = __builtin_amdgcn_mfma_f32_32x32x16_f16(a0.h, b0.h,  acc[0][0], 0,0,0);
        acc[0][1] = __builtin_amdgcn_mfma_f32_32x32x16_f16(a0.h, b1u.h, acc[0][1], 0,0,0);
        acc[1][0] = __builtin_amdgcn_mfma_f32_32x32x16_f16(a1.h, b0.h,  acc[1][0], 0,0,0);
        acc[1][1] = __builtin_amdgcn_mfma_f32_32x32x16_f16(a1.h, b1u.h, acc[1][1], 0,0,0);
      }
    }

    // epilogue: relu + w2-weighted reduce; C/D row = (r&3)+8*(r>>2)+4*h
    #pragma unroll
    for (int i=0;i<2;i++){
      #pragma unroll
      for (int r=0;r<16;r++){
        float p = w2v[0]*fmaxf(acc[i][0][r] + b1v[0], 0.f)
                + w2v[1]*fmaxf(acc[i][1][r] + b1v[1], 0.f);
        p += __shfl_xor(p, 1);
        p += __shfl_xor(p, 2);
        p += __shfl_xor(p, 4);
        p += __shfl_xor(p, 8);
        p += __shfl_xor(p, 16);
        if (l31 == 0){
          int row = m0 + wm + 32*i + (r&3) + 8*(r>>2) + 4*h;
          atomicAdd(&logit[row], p);
        }
      }
    }
  }

  gsync(sc + 1);

  // ---- phase 2: flags + first/last + bounds (rows [bid*32, +32)) ----
  {
    float b2 = b2p[0];
    if (tid < 32){
      int g = bid*32 + tid;
      int s = g & (S_-1);
      bool any = false;
      if (s >= 2){
        float z0 = logit[g] + b2;
        float z1 = logit[g-1] + b2;
        float z2 = logit[g-2] + b2;
        const float THR = 0.8472978603872037f;  // ln(0.7/0.3)
        bool run = (z0 > THR) & (z1 > THR) & (z2 > THR);
        float na = fmaxf(sqrtf(n2o[g-1]), 1e-8f);
        float nb = fmaxf(sqrtf(n2o[g]), 1e-8f);
        bool cosr = (dto[g-1] < 0.3f*na*nb) & (z0 > 0.f);
        any = run | cosr;
      }
      int mn = any ? s : 0x7FFFFFFF;
      int mx = any ? s : -1;
      #pragma unroll
      for (int off=16; off>0; off>>=1){
        mn = min(mn, __shfl_down(mn, off, 32));
        mx = max(mx, __shfl_down(mx, off, 32));
      }
      if (tid == 0){
        atomicMin(&fl[0], mn);
        atomicMax(&fl[1], mx);
      }
    }
    __syncthreads();
    if (tid == 0){
      __threadfence();
      int old = atomicAdd(&fl[2], 1);
      if (old == NBLK - 1){
        int f = atomicMin(&fl[0], 0x7FFFFFFF);
        int l = atomicMax(&fl[1], (int)0x80000000);
        if (l < 0){ ob[0] = -1.f; ob[1] = -1.f; }
        else {
          int st = f - 2; if (st < 0) st = 0;
          int en = l + 2; if (en > S_-1) en = S_-1;
          ob[0] = (float)st; ob[1] = (float)en;
        }
      }
    }
  }
}

// ---------- segment pooling (chunks with seg>=8 at entry exit early) ----------
__global__ void k_pool(const float* __restrict__ X, const int* __restrict__ mask,
                       const int* __restrict__ cb, float* __restrict__ gsums,
                       float* __restrict__ gcnt){
  int c = blockIdx.x, b = blockIdx.y, tid = threadIdx.x;
  int base = cb[b*16 + c];
  if (base >= 8) return;
  __shared__ float lsum[8*1024];
  __shared__ int seg[256];
  __shared__ float lcnt[8];
  __shared__ int send_s;
  for (int e=tid; e<8192; e+=256) lsum[e] = 0.f;
  if (tid==0){
    float cnts[8] = {0,0,0,0,0,0,0,0};
    const int* mrow = mask + (size_t)b*S_ + c*256;
    int running = base, i = 0;
    for (; i<256; ++i){
      if (running >= 8) break;
      seg[i] = running;
      cnts[running] += 1.f;
      running += mrow[i];
    }
    send_s = i;
    #pragma unroll
    for (int p=0;p<8;p++) lcnt[p] = cnts[p];
  }
  __syncthreads();
  int send = send_s;
  for (int s2=0; s2<send; ++s2){
    int sg = seg[s2];
    size_t gb = ((size_t)(b*S_ + c*256 + s2))*D_;
    #pragma unroll
    for (int q=0;q<4;q++){
      int d = tid + q*256;
      lsum[sg*1024 + d] += X[gb + d];
    }
  }
  __syncthreads();
  for (int e=tid; e<8192; e+=256){
    float v = lsum[e];
    if (v != 0.f) atomicAdd(&gsums[(size_t)b*8192 + e], v);
  }
  if (tid < 8){
    float v = lcnt[tid];
    if (v != 0.f) atomicAdd(&gcnt[b*8 + tid], v);
  }
}

// ---------- patches = pooled @ proj_w + proj_b (k-split) ----------
__global__ __launch_bounds__(256) void k_patch(const float* __restrict__ gsums,
                        const float* __restrict__ gcnt,
                        const float* __restrict__ pw, const float* __restrict__ pb,
                        float* __restrict__ out){
  __shared__ float pool[8192];
  __shared__ float red[2048];
  int b = blockIdx.y, cx = blockIdx.x, tid = threadIdx.x;
  const float4* gs4 = (const float4*)(gsums + (size_t)b*8192);
  float4* pool4 = (float4*)pool;
  for (int e4=tid; e4<2048; e4+=256){
    int p = e4>>8;
    float inv = 1.f / fmaxf(gcnt[b*8 + p], 1.f);
    float4 v = gs4[e4];
    v.x*=inv; v.y*=inv; v.z*=inv; v.w*=inv;
    pool4[e4] = v;
  }
  __syncthreads();
  int c = tid & 31, ks = tid >> 5;
  int col = cx*32 + c;
  float acc[8] = {0,0,0,0,0,0,0,0};
  for (int k=ks*128; k<ks*128+128; ++k){
    float w = pw[(size_t)k*D_ + col];
    #pragma unroll
    for (int p=0;p<8;p++) acc[p] += pool[p*1024 + k]*w;
  }
  #pragma unroll
  for (int p=0;p<8;p++) red[tid*8 + p] = acc[p];
  __syncthreads();
  {
    int p = tid>>5, cc = tid&31;
    float s = 0.f;
    #pragma unroll
    for (int k2=0;k2<8;k2++) s += red[(k2*32 + cc)*8 + p];
    out[(size_t)(b*8+p)*D_ + cx*32 + cc] = s + pb[cx*32 + cc];
  }
}

extern "C" void kernel_launch(void* const* d_in, const int* in_sizes, int n_in,
                              void* d_out, int out_size, void* d_ws, size_t ws_size,
                              hipStream_t stream){
  const float* latent = (const float*)d_in[0];
  const int*   mask   = (const int*)d_in[1];
  const float* proj_w = (const float*)d_in[2];
  const float* proj_b = (const float*)d_in[3];
  const float* eos_w1 = (const float*)d_in[4];
  const float* eos_b1 = (const float*)d_in[5];
  const float* eos_w2 = (const float*)d_in[6];
  const float* eos_b2 = (const float*)d_in[7];
  float* out = (float*)d_out;

  char* ws = (char*)d_ws;
  unsigned short* W1T = (unsigned short*)ws;              // 1 MB
  unsigned short* Xh  = (unsigned short*)(ws + 1048576);  // 64 MB
  float* fbase = (float*)(ws + 1048576 + 67108864);
  float* logit = fbase;                            // 32768
  float* norm2 = fbase + 32768;                    // 32768
  float* dotv  = fbase + 65536;                    // 32768
  float* gsums = fbase + 98304;                    // 65536
  float* gcnt  = fbase + 163840;                   // 64
  int* chunkbase = (int*)(fbase + 163904);         // 128 ints
  int* fl        = (int*)(fbase + 164032);         // 3 ints
  int* sc        = (int*)(fbase + 164035);         // 2 ints

  k_init<<<1, 64, 0, stream>>>(sc, fl);
  k_mega<<<NBLK, 256, 0, stream>>>(latent, mask, eos_w1, eos_b1, eos_w2, eos_b2,
                                   Xh, W1T, norm2, dotv, logit, gsums, gcnt,
                                   chunkbase, fl, sc, out + 65536);
  k_pool<<<dim3(16,8), 256, 0, stream>>>(latent, mask, chunkbase, gsums, gcnt);
  k_patch<<<dim3(32,8), 256, 0, stream>>>(gsums, gcnt, proj_w, proj_b, out);
}

// Round 6
// 307.509 us; speedup vs baseline: 1.9947x; 1.9947x over previous
//
#include <hip/hip_runtime.h>
#include <hip/hip_fp16.h>
#include <cstdint>
#include <cstddef>

#define B_ 8
#define S_ 4096
#define D_ 1024
#define H_ 512
#define M_ (B_*S_)

typedef __attribute__((ext_vector_type(8))) _Float16 half8;
typedef __attribute__((ext_vector_type(16))) float f16v;

union HU { int4 v; half8 h; };

__device__ inline unsigned short f2h(float f){
  _Float16 h = (_Float16)f;
  return __builtin_bit_cast(unsigned short, h);
}

// ---------- fused pre-pass ----------
// blocks [0,512):   per-row norm^2 + adjacent dot + fp32->f16 cast of X
// blocks [512,1024): W1^T f16 transpose
// blocks [1024,1032): mask prefix counts + zeroing + seeds
__global__ __launch_bounds__(256) void k_pre(const float* __restrict__ X,
    float* __restrict__ n2o, float* __restrict__ dto, unsigned short* __restrict__ Xh,
    const float* __restrict__ w1, unsigned short* __restrict__ w1t,
    const int* __restrict__ mask, int* __restrict__ cb, float* __restrict__ logit,
    float* __restrict__ gsums, float* __restrict__ gcnt, int* __restrict__ fl){
  __shared__ float tile[32][33];
  __shared__ int sc[256];
  int bid = blockIdx.x, tid = threadIdx.x;
  if (bid < 512){
    int wave = tid>>6, lane = tid&63;
    int g0 = (bid*4 + wave)*16;
    const float4* Xv = (const float4*)X;
    ushort4* Xhv = (ushort4*)Xh;
    float4 pv[4];
    if ((g0 & (S_-1)) != 0){
      size_t bb = (size_t)(g0-1)*256;
      #pragma unroll
      for (int q=0;q<4;q++) pv[q] = Xv[bb + q*64 + lane];
    } else {
      #pragma unroll
      for (int q=0;q<4;q++) pv[q] = make_float4(0.f,0.f,0.f,0.f);
    }
    for (int r=0;r<16;r++){
      int g = g0 + r;
      size_t bb = (size_t)g*256;
      float4 cv[4];
      #pragma unroll
      for (int q=0;q<4;q++) cv[q] = Xv[bb + q*64 + lane];
      float n2=0.f, dp=0.f;
      #pragma unroll
      for (int q=0;q<4;q++){
        n2 += cv[q].x*cv[q].x + cv[q].y*cv[q].y + cv[q].z*cv[q].z + cv[q].w*cv[q].w;
        dp += pv[q].x*cv[q].x + pv[q].y*cv[q].y + pv[q].z*cv[q].z + pv[q].w*cv[q].w;
      }
      #pragma unroll
      for (int q=0;q<4;q++){
        ushort4 u;
        u.x = f2h(cv[q].x); u.y = f2h(cv[q].y); u.z = f2h(cv[q].z); u.w = f2h(cv[q].w);
        Xhv[bb + q*64 + lane] = u;
      }
      #pragma unroll
      for (int off=32; off>0; off>>=1){
        n2 += __shfl_down(n2, off);
        dp += __shfl_down(dp, off);
      }
      if (lane==0){
        n2o[g] = n2;
        if ((g & (S_-1)) != 0) dto[g-1] = dp;
      }
      #pragma unroll
      for (int q=0;q<4;q++) pv[q] = cv[q];
    }
  } else if (bid < 1024){
    int b = bid - 512;
    int n0 = (b&15)*32, k0 = (b>>4)*32;
    int tx = tid&31, ty = tid>>5;
    #pragma unroll
    for (int i=0;i<4;i++) tile[ty+8*i][tx] = w1[(size_t)(k0+ty+8*i)*H_ + n0+tx];
    __syncthreads();
    #pragma unroll
    for (int i=0;i<4;i++) w1t[(size_t)(n0+ty+8*i)*D_ + k0+tx] = f2h(tile[tx][ty+8*i]);
  } else {
    int bb = bid - 1024;   // 0..7
    const int* mrow = mask + (size_t)bb*S_ + tid*16;
    int s = 0;
    #pragma unroll
    for (int i=0;i<16;i++) s += mrow[i];
    sc[tid] = s;
    __syncthreads();
    for (int off=1; off<256; off<<=1){
      int v = (tid>=off) ? sc[tid-off] : 0;
      __syncthreads();
      sc[tid] += v;
      __syncthreads();
    }
    if ((tid & 15) == 0) cb[bb*16 + (tid>>4)] = (tid==0) ? 0 : sc[tid-1];
    float4* lz = (float4*)(logit + bb*4096);
    #pragma unroll
    for (int e=tid; e<1024; e+=256) lz[e] = make_float4(0.f,0.f,0.f,0.f);
    float4* gz = (float4*)(gsums + (size_t)bb*8192);
    for (int e=tid; e<2048; e+=256) gz[e] = make_float4(0.f,0.f,0.f,0.f);
    if (bb==0){
      if (tid < 64) gcnt[tid] = 0.f;
      if (tid == 64){ fl[0] = 0x7FFFFFFF; fl[1] = -1; fl[2] = 0; }
    }
  }
}

// ---------- fused EOS MLP ----------
// 32x32x16 f16 MFMA, BK=32, double-buffered LDS, one barrier per kt.
// Grid mapping: m INNERMOST so the 4 n-blocks sharing one Xh m-slice land on
// the same XCD (bid%8 invariant in n) -> m-slice fetched once into that L2.
#define AS1 __attribute__((address_space(1)))
#define AS3 __attribute__((address_space(3)))

#define STAGE(kt_, nb_) do { int k0e = (kt_)*32; \
  char* abase = (char*)As[nb_]; char* bbase = (char*)Bs[nb_]; \
  _Pragma("unroll") for (int q=0;q<2;q++){ \
    __builtin_amdgcn_global_load_lds((const AS1 void*)(agp[q]+k0e), (AS3 void*)(abase+aldo[q]),16,0,0); \
    __builtin_amdgcn_global_load_lds((const AS1 void*)(bgp[q]+k0e), (AS3 void*)(bbase+bldo[q]),16,0,0); } \
} while(0)

__global__ __launch_bounds__(256) void k_mlp(const unsigned short* __restrict__ Xh,
    const unsigned short* __restrict__ W1T, const float* __restrict__ b1,
    const float* __restrict__ w2, float* __restrict__ logit){
  __shared__ __align__(16) unsigned short As[2][128*32];   // 2 x 8 KB
  __shared__ __align__(16) unsigned short Bs[2][128*32];   // 2 x 8 KB
  int tid = threadIdx.x;
  int wave = tid>>6, lane = tid&63;
  int l31 = lane&31, h = lane>>5;
  int m0 = (blockIdx.x & 255)*128, n0 = (blockIdx.x >> 8)*128;  // m innermost!
  int wm = (wave>>1)*64, wn = (wave&1)*64;
  f16v acc[2][2] = {};

  // staging: issue q covers 16 rows (rb=wave*32+q*16), 64 B each.
  // lane i -> row rb+(i>>2), slot i&3, global chunk c = (i&3) ^ ((row>>1)&3).
  int srow = lane>>2;
  const unsigned short* agp[2]; const unsigned short* bgp[2];
  unsigned aldo[2], bldo[2];
  #pragma unroll
  for (int q=0;q<2;q++){
    int rb = wave*32 + q*16;
    int r  = rb + srow;
    int c  = (lane&3) ^ ((r>>1)&3);
    agp[q] = Xh  + (size_t)(m0 + r)*D_ + c*8;
    bgp[q] = W1T + (size_t)(n0 + r)*D_ + c*8;
    aldo[q] = rb*64;
    bldo[q] = rb*64;
  }

  // fragment LDS byte offsets: row r, chunk c=kk*2+h -> r*64 + ((c^((r>>1)&3))<<4)
  unsigned aoff[2][2], boff[2][2];
  #pragma unroll
  for (int i=0;i<2;i++){
    int rm = wm + 32*i + l31;
    int rn = wn + 32*i + l31;
    #pragma unroll
    for (int kk=0;kk<2;kk++){
      int c = kk*2 + h;
      aoff[i][kk] = rm*64 + ((c ^ ((rm>>1)&3))<<4);
      boff[i][kk] = rn*64 + ((c ^ ((rn>>1)&3))<<4);
    }
  }

  // prefetch epilogue constants before the hot loop
  float b1v[2], w2v[2];
  #pragma unroll
  for (int j=0;j<2;j++){
    int n = n0 + wn + 32*j + l31;
    b1v[j] = b1[n]; w2v[j] = w2[n];
  }

  STAGE(0, 0);
  for (int kt=0; kt<32; ++kt){
    __syncthreads();                    // drains stage(kt)
    if (kt < 31) STAGE(kt+1, (kt+1)&1); // prefetch flies during this kt's MFMAs
    const char* ab = (const char*)As[kt&1];
    const char* bb = (const char*)Bs[kt&1];
    #pragma unroll
    for (int kk=0;kk<2;kk++){
      HU a0, a1, b0, b1u;
      a0.v  = *(const int4*)(ab + aoff[0][kk]);
      a1.v  = *(const int4*)(ab + aoff[1][kk]);
      b0.v  = *(const int4*)(bb + boff[0][kk]);
      b1u.v = *(const int4*)(bb + boff[1][kk]);
      acc[0][0] = __builtin_amdgcn_mfma_f32_32x32x16_f16(a0.h, b0.h,  acc[0][0], 0,0,0);
      acc[0][1] = __builtin_amdgcn_mfma_f32_32x32x16_f16(a0.h, b1u.h, acc[0][1], 0,0,0);
      acc[1][0] = __builtin_amdgcn_mfma_f32_32x32x16_f16(a1.h, b0.h,  acc[1][0], 0,0,0);
      acc[1][1] = __builtin_amdgcn_mfma_f32_32x32x16_f16(a1.h, b1u.h, acc[1][1], 0,0,0);
    }
  }

  // epilogue: relu + w2-weighted reduction over this block's 128 columns
  // C/D: col = lane&31, row = (r&3) + 8*(r>>2) + 4*(lane>>5)
  #pragma unroll
  for (int i=0;i<2;i++){
    #pragma unroll
    for (int r=0;r<16;r++){
      float p = w2v[0]*fmaxf(acc[i][0][r] + b1v[0], 0.f)
              + w2v[1]*fmaxf(acc[i][1][r] + b1v[1], 0.f);
      p += __shfl_xor(p, 1);
      p += __shfl_xor(p, 2);
      p += __shfl_xor(p, 4);
      p += __shfl_xor(p, 8);
      p += __shfl_xor(p, 16);
      if (l31 == 0){
        int row = m0 + wm + 32*i + (r&3) + 8*(r>>2) + 4*h;
        atomicAdd(&logit[row], p);
      }
    }
  }
}

// ---------- segment pooling (chunks with seg>=8 at entry exit early) ----------
__global__ void k_pool(const float* __restrict__ X, const int* __restrict__ mask,
                       const int* __restrict__ cb, float* __restrict__ gsums,
                       float* __restrict__ gcnt){
  int c = blockIdx.x, b = blockIdx.y, tid = threadIdx.x;
  int base = cb[b*16 + c];
  if (base >= 8) return;
  __shared__ float lsum[8*1024];
  __shared__ int seg[256];
  __shared__ float lcnt[8];
  __shared__ int send_s;
  for (int e=tid; e<8192; e+=256) lsum[e] = 0.f;
  if (tid==0){
    float cnts[8] = {0,0,0,0,0,0,0,0};
    const int* mrow = mask + (size_t)b*S_ + c*256;
    int running = base, i = 0;
    for (; i<256; ++i){
      if (running >= 8) break;
      seg[i] = running;
      cnts[running] += 1.f;
      running += mrow[i];
    }
    send_s = i;
    #pragma unroll
    for (int p=0;p<8;p++) lcnt[p] = cnts[p];
  }
  __syncthreads();
  int send = send_s;
  for (int s2=0; s2<send; ++s2){
    int sg = seg[s2];
    size_t gb = ((size_t)(b*S_ + c*256 + s2))*D_;
    #pragma unroll
    for (int q=0;q<4;q++){
      int d = tid + q*256;
      lsum[sg*1024 + d] += X[gb + d];
    }
  }
  __syncthreads();
  for (int e=tid; e<8192; e+=256){
    float v = lsum[e];
    if (v != 0.f) atomicAdd(&gsums[(size_t)b*8192 + e], v);
  }
  if (tid < 8){
    float v = lcnt[tid];
    if (v != 0.f) atomicAdd(&gcnt[b*8 + tid], v);
  }
}

// ---------- patches = pooled @ proj_w + proj_b (k-split) ----------
__global__ __launch_bounds__(256) void k_patch(const float* __restrict__ gsums,
                        const float* __restrict__ gcnt,
                        const float* __restrict__ pw, const float* __restrict__ pb,
                        float* __restrict__ out){
  __shared__ float pool[8192];
  __shared__ float red[2048];
  int b = blockIdx.y, cx = blockIdx.x, tid = threadIdx.x;
  const float4* gs4 = (const float4*)(gsums + (size_t)b*8192);
  float4* pool4 = (float4*)pool;
  for (int e4=tid; e4<2048; e4+=256){
    int p = e4>>8;
    float inv = 1.f / fmaxf(gcnt[b*8 + p], 1.f);
    float4 v = gs4[e4];
    v.x*=inv; v.y*=inv; v.z*=inv; v.w*=inv;
    pool4[e4] = v;
  }
  __syncthreads();
  int c = tid & 31, ks = tid >> 5;
  int col = cx*32 + c;
  float acc[8] = {0,0,0,0,0,0,0,0};
  for (int k=ks*128; k<ks*128+128; ++k){
    float w = pw[(size_t)k*D_ + col];
    #pragma unroll
    for (int p=0;p<8;p++) acc[p] += pool[p*1024 + k]*w;
  }
  #pragma unroll
  for (int p=0;p<8;p++) red[tid*8 + p] = acc[p];
  __syncthreads();
  {
    int p = tid>>5, cc = tid&31;
    float s = 0.f;
    #pragma unroll
    for (int k2=0;k2<8;k2++) s += red[(k2*32 + cc)*8 + p];
    out[(size_t)(b*8+p)*D_ + cx*32 + cc] = s + pb[cx*32 + cc];
  }
}

// ---------- flags + first/last reduction + fused bounds (last block) ----------
__global__ void k_flagsb(const float* __restrict__ logit, const float* __restrict__ n2,
                        const float* __restrict__ dt, const float* __restrict__ b2p,
                        int* __restrict__ fl, float* __restrict__ ob){
  int g = blockIdx.x*256 + threadIdx.x;
  float b2 = b2p[0];
  int s = g & (S_-1);
  bool any = false;
  if (s >= 2){
    float z0 = logit[g] + b2;
    float z1 = logit[g-1] + b2;
    float z2 = logit[g-2] + b2;
    const float THR = 0.8472978603872037f;  // ln(0.7/0.3)
    bool run = (z0 > THR) & (z1 > THR) & (z2 > THR);
    float na = fmaxf(sqrtf(n2[g-1]), 1e-8f);
    float nb = fmaxf(sqrtf(n2[g]), 1e-8f);
    bool cosr = (dt[g-1] < 0.3f*na*nb) & (z0 > 0.f);
    any = run | cosr;
  }
  int mn = any ? s : 0x7FFFFFFF;
  int mx = any ? s : -1;
  #pragma unroll
  for (int off=32; off>0; off>>=1){
    mn = min(mn, __shfl_down(mn, off));
    mx = max(mx, __shfl_down(mx, off));
  }
  if ((threadIdx.x & 63) == 0){
    atomicMin(&fl[0], mn);
    atomicMax(&fl[1], mx);
  }
  __syncthreads();
  if (threadIdx.x == 0){
    __threadfence();
    int old = atomicAdd(&fl[2], 1);
    if (old == gridDim.x - 1){
      int f = atomicMin(&fl[0], 0x7FFFFFFF);
      int l = atomicMax(&fl[1], (int)0x80000000);
      if (l < 0){ ob[0] = -1.f; ob[1] = -1.f; }
      else {
        int st = f - 2; if (st < 0) st = 0;
        int en = l + 2; if (en > S_-1) en = S_-1;
        ob[0] = (float)st; ob[1] = (float)en;
      }
    }
  }
}

extern "C" void kernel_launch(void* const* d_in, const int* in_sizes, int n_in,
                              void* d_out, int out_size, void* d_ws, size_t ws_size,
                              hipStream_t stream){
  const float* latent = (const float*)d_in[0];
  const int*   mask   = (const int*)d_in[1];
  const float* proj_w = (const float*)d_in[2];
  const float* proj_b = (const float*)d_in[3];
  const float* eos_w1 = (const float*)d_in[4];
  const float* eos_b1 = (const float*)d_in[5];
  const float* eos_w2 = (const float*)d_in[6];
  const float* eos_b2 = (const float*)d_in[7];
  float* out = (float*)d_out;

  char* ws = (char*)d_ws;
  unsigned short* W1T = (unsigned short*)ws;              // 1 MB
  unsigned short* Xh  = (unsigned short*)(ws + 1048576);  // 64 MB
  float* fbase = (float*)(ws + 1048576 + 67108864);
  float* logit = fbase;                            // 32768
  float* norm2 = fbase + 32768;                    // 32768
  float* dotv  = fbase + 65536;                    // 32768
  float* gsums = fbase + 98304;                    // 65536
  float* gcnt  = fbase + 163840;                   // 64
  int* chunkbase = (int*)(fbase + 163904);         // 128 ints
  int* fl        = (int*)(fbase + 164032);         // 3 ints

  k_pre<<<1032, 256, 0, stream>>>(latent, norm2, dotv, Xh, eos_w1, W1T, mask,
                                  chunkbase, logit, gsums, gcnt, fl);
  k_pool<<<dim3(16,8), 256, 0, stream>>>(latent, mask, chunkbase, gsums, gcnt);
  k_patch<<<dim3(32,8), 256, 0, stream>>>(gsums, gcnt, proj_w, proj_b, out);
  k_mlp<<<1024, 256, 0, stream>>>(Xh, W1T, eos_b1, eos_w2, logit);
  k_flagsb<<<128, 256, 0, stream>>>(logit, norm2, dotv, eos_b2, fl, out + 65536);
}

// Round 7
// 298.698 us; speedup vs baseline: 2.0536x; 1.0295x over previous
//
#include <hip/hip_runtime.h>
#include <hip/hip_fp16.h>
#include <cstdint>
#include <cstddef>

#define B_ 8
#define S_ 4096
#define D_ 1024
#define H_ 512
#define M_ (B_*S_)

typedef __attribute__((ext_vector_type(16))) float f16v;

__device__ inline unsigned char f2fp8(float f){
  int v = __builtin_amdgcn_cvt_pk_fp8_f32(f, f, 0, false);
  return (unsigned char)(v & 0xFF);
}

// ---------- fused pre-pass ----------
// blocks [0,512):    per-row norm^2 + adjacent dot + fp32->fp8 cast of X
// blocks [512,1024): W1^T fp8 transpose (scaled x64 to dodge e4m3 subnormals)
// blocks [1024,1032): mask prefix counts + zeroing + seeds
__global__ __launch_bounds__(256) void k_pre(const float* __restrict__ X,
    float* __restrict__ n2o, float* __restrict__ dto, unsigned char* __restrict__ X8,
    const float* __restrict__ w1, unsigned char* __restrict__ w1t8,
    const int* __restrict__ mask, int* __restrict__ cb, float* __restrict__ logit,
    float* __restrict__ gsums, float* __restrict__ gcnt, int* __restrict__ fl){
  __shared__ float tile[32][33];
  __shared__ int sc[256];
  int bid = blockIdx.x, tid = threadIdx.x;
  if (bid < 512){
    int wave = tid>>6, lane = tid&63;
    int g0 = (bid*4 + wave)*16;
    const float4* Xv = (const float4*)X;
    int* X8i = (int*)X8;
    float4 pv[4];
    if ((g0 & (S_-1)) != 0){
      size_t bb = (size_t)(g0-1)*256;
      #pragma unroll
      for (int q=0;q<4;q++) pv[q] = Xv[bb + q*64 + lane];
    } else {
      #pragma unroll
      for (int q=0;q<4;q++) pv[q] = make_float4(0.f,0.f,0.f,0.f);
    }
    for (int r=0;r<16;r++){
      int g = g0 + r;
      size_t bb = (size_t)g*256;
      float4 cv[4];
      #pragma unroll
      for (int q=0;q<4;q++) cv[q] = Xv[bb + q*64 + lane];
      float n2=0.f, dp=0.f;
      #pragma unroll
      for (int q=0;q<4;q++){
        n2 += cv[q].x*cv[q].x + cv[q].y*cv[q].y + cv[q].z*cv[q].z + cv[q].w*cv[q].w;
        dp += pv[q].x*cv[q].x + pv[q].y*cv[q].y + pv[q].z*cv[q].z + pv[q].w*cv[q].w;
      }
      #pragma unroll
      for (int q=0;q<4;q++){
        int pk = __builtin_amdgcn_cvt_pk_fp8_f32(cv[q].x, cv[q].y, 0, false);
        pk = __builtin_amdgcn_cvt_pk_fp8_f32(cv[q].z, cv[q].w, pk, true);
        X8i[bb + q*64 + lane] = pk;
      }
      #pragma unroll
      for (int off=32; off>0; off>>=1){
        n2 += __shfl_down(n2, off);
        dp += __shfl_down(dp, off);
      }
      if (lane==0){
        n2o[g] = n2;
        if ((g & (S_-1)) != 0) dto[g-1] = dp;
      }
      #pragma unroll
      for (int q=0;q<4;q++) pv[q] = cv[q];
    }
  } else if (bid < 1024){
    int b = bid - 512;
    int n0 = (b&15)*32, k0 = (b>>4)*32;
    int tx = tid&31, ty = tid>>5;
    #pragma unroll
    for (int i=0;i<4;i++) tile[ty+8*i][tx] = w1[(size_t)(k0+ty+8*i)*H_ + n0+tx];
    __syncthreads();
    #pragma unroll
    for (int i=0;i<4;i++)
      w1t8[(size_t)(n0+ty+8*i)*D_ + k0+tx] = f2fp8(64.f * tile[tx][ty+8*i]);
  } else {
    int bb = bid - 1024;   // 0..7
    const int* mrow = mask + (size_t)bb*S_ + tid*16;
    int s = 0;
    #pragma unroll
    for (int i=0;i<16;i++) s += mrow[i];
    sc[tid] = s;
    __syncthreads();
    for (int off=1; off<256; off<<=1){
      int v = (tid>=off) ? sc[tid-off] : 0;
      __syncthreads();
      sc[tid] += v;
      __syncthreads();
    }
    if ((tid & 15) == 0) cb[bb*16 + (tid>>4)] = (tid==0) ? 0 : sc[tid-1];
    float4* lz = (float4*)(logit + bb*4096);
    #pragma unroll
    for (int e=tid; e<1024; e+=256) lz[e] = make_float4(0.f,0.f,0.f,0.f);
    float4* gz = (float4*)(gsums + (size_t)bb*8192);
    for (int e=tid; e<2048; e+=256) gz[e] = make_float4(0.f,0.f,0.f,0.f);
    if (bb==0){
      if (tid < 64) gcnt[tid] = 0.f;
      if (tid == 64){ fl[0] = 0x7FFFFFFF; fl[1] = -1; fl[2] = 0; }
    }
  }
}

// ---------- fused EOS MLP, fp8 ----------
// 32x32x16 fp8 MFMA, BK=64 (64 B rows), double-buffered LDS, one barrier/kt.
// 16B-slot XOR swizzle: slot = t ^ y(r), y(r) = ((r>>1)&3) ^ ((r>>3)&3).
// Anti-convoy: each block starts its K loop at a rotated kt.
#define AS1 __attribute__((address_space(1)))
#define AS3 __attribute__((address_space(3)))

#define STAGE(ktp_, nb_) do { int k0e = (ktp_)*64; \
  char* abase = (char*)As[nb_]; char* bbase = (char*)Bs[nb_]; \
  _Pragma("unroll") for (int q=0;q<2;q++){ \
    __builtin_amdgcn_global_load_lds((const AS1 void*)(agp[q]+k0e), (AS3 void*)(abase+aldo[q]),16,0,0); \
    __builtin_amdgcn_global_load_lds((const AS1 void*)(bgp[q]+k0e), (AS3 void*)(bbase+bldo[q]),16,0,0); } \
} while(0)

__global__ __launch_bounds__(256) void k_mlp(const unsigned char* __restrict__ X8,
    const unsigned char* __restrict__ W1T8, const float* __restrict__ b1,
    const float* __restrict__ w2, float* __restrict__ logit){
  __shared__ __align__(16) unsigned char As[2][128*64];   // 2 x 8 KB
  __shared__ __align__(16) unsigned char Bs[2][128*64];   // 2 x 8 KB
  int tid = threadIdx.x;
  int wave = tid>>6, lane = tid&63;
  int l31 = lane&31, h = lane>>5;
  int m0 = (blockIdx.x & 255)*128, n0 = (blockIdx.x >> 8)*128;  // m innermost
  int rot = (((blockIdx.x >> 8)*4) + (blockIdx.x & 3)) & 15;     // k-rotation
  int wm = (wave>>1)*64, wn = (wave&1)*64;
  f16v acc[2][2] = {};

  // staging: instr q covers 16 rows (rb=wave*32+q*16), 64 B each; 4 lanes/row.
  // lane i -> row rb+(i>>2), LDS slot i&3, global 16B-chunk c = (i&3)^y(r).
  int srow = lane>>2, sslot = lane&3;
  const unsigned char* agp[2]; const unsigned char* bgp[2];
  unsigned aldo[2], bldo[2];
  #pragma unroll
  for (int q=0;q<2;q++){
    int rb = wave*32 + q*16;
    int r  = rb + srow;
    int y  = ((r>>1)&3) ^ ((r>>3)&3);
    int c  = sslot ^ y;
    agp[q] = X8  + (size_t)(m0 + r)*D_ + c*16;
    bgp[q] = W1T8 + (size_t)(n0 + r)*D_ + c*16;
    aldo[q] = rb*64;
    bldo[q] = rb*64;
  }

  // fragment LDS byte offsets: row r, k-step t -> r*64 + ((t^y(r))<<4) + h*8
  unsigned aoff[2][4], boff[2][4];
  #pragma unroll
  for (int i=0;i<2;i++){
    int rm = wm + 32*i + l31;
    int rn = wn + 32*i + l31;
    int ym = ((rm>>1)&3) ^ ((rm>>3)&3);
    int yn = ((rn>>1)&3) ^ ((rn>>3)&3);
    #pragma unroll
    for (int t=0;t<4;t++){
      aoff[i][t] = rm*64 + ((t ^ ym)<<4) + h*8;
      boff[i][t] = rn*64 + ((t ^ yn)<<4) + h*8;
    }
  }

  // epilogue constants (undo the x64 weight scale)
  float b1v[2], w2v[2];
  #pragma unroll
  for (int j=0;j<2;j++){
    int n = n0 + wn + 32*j + l31;
    b1v[j] = b1[n] * 64.f;
    w2v[j] = w2[n] * (1.f/64.f);
  }

  STAGE(rot, 0);
  for (int kt=0; kt<16; ++kt){
    __syncthreads();                                   // drains stage(kt)
    if (kt < 15) STAGE((kt+1+rot)&15, (kt+1)&1);       // prefetch during MFMAs
    const char* ab = (const char*)As[kt&1];
    const char* bb = (const char*)Bs[kt&1];
    #pragma unroll
    for (int t=0;t<4;t++){
      long a0 = *(const long*)(ab + aoff[0][t]);
      long a1 = *(const long*)(ab + aoff[1][t]);
      long b0 = *(const long*)(bb + boff[0][t]);
      long b1u = *(const long*)(bb + boff[1][t]);
      acc[0][0] = __builtin_amdgcn_mfma_f32_32x32x16_fp8_fp8(a0, b0,  acc[0][0], 0,0,0);
      acc[0][1] = __builtin_amdgcn_mfma_f32_32x32x16_fp8_fp8(a0, b1u, acc[0][1], 0,0,0);
      acc[1][0] = __builtin_amdgcn_mfma_f32_32x32x16_fp8_fp8(a1, b0,  acc[1][0], 0,0,0);
      acc[1][1] = __builtin_amdgcn_mfma_f32_32x32x16_fp8_fp8(a1, b1u, acc[1][1], 0,0,0);
    }
  }

  // epilogue: relu + w2-weighted reduction over this block's 128 columns
  // C/D: col = lane&31, row = (r&3) + 8*(r>>2) + 4*(lane>>5)
  #pragma unroll
  for (int i=0;i<2;i++){
    #pragma unroll
    for (int r=0;r<16;r++){
      float p = w2v[0]*fmaxf(acc[i][0][r] + b1v[0], 0.f)
              + w2v[1]*fmaxf(acc[i][1][r] + b1v[1], 0.f);
      p += __shfl_xor(p, 1);
      p += __shfl_xor(p, 2);
      p += __shfl_xor(p, 4);
      p += __shfl_xor(p, 8);
      p += __shfl_xor(p, 16);
      if (l31 == 0){
        int row = m0 + wm + 32*i + (r&3) + 8*(r>>2) + 4*h;
        atomicAdd(&logit[row], p);
      }
    }
  }
}

// ---------- segment pooling (chunks with seg>=8 at entry exit early) ----------
__global__ void k_pool(const float* __restrict__ X, const int* __restrict__ mask,
                       const int* __restrict__ cb, float* __restrict__ gsums,
                       float* __restrict__ gcnt){
  int c = blockIdx.x, b = blockIdx.y, tid = threadIdx.x;
  int base = cb[b*16 + c];
  if (base >= 8) return;
  __shared__ float lsum[8*1024];
  __shared__ int seg[256];
  __shared__ float lcnt[8];
  __shared__ int send_s;
  for (int e=tid; e<8192; e+=256) lsum[e] = 0.f;
  if (tid==0){
    float cnts[8] = {0,0,0,0,0,0,0,0};
    const int* mrow = mask + (size_t)b*S_ + c*256;
    int running = base, i = 0;
    for (; i<256; ++i){
      if (running >= 8) break;
      seg[i] = running;
      cnts[running] += 1.f;
      running += mrow[i];
    }
    send_s = i;
    #pragma unroll
    for (int p=0;p<8;p++) lcnt[p] = cnts[p];
  }
  __syncthreads();
  int send = send_s;
  for (int s2=0; s2<send; ++s2){
    int sg = seg[s2];
    size_t gb = ((size_t)(b*S_ + c*256 + s2))*D_;
    #pragma unroll
    for (int q=0;q<4;q++){
      int d = tid + q*256;
      lsum[sg*1024 + d] += X[gb + d];
    }
  }
  __syncthreads();
  for (int e=tid; e<8192; e+=256){
    float v = lsum[e];
    if (v != 0.f) atomicAdd(&gsums[(size_t)b*8192 + e], v);
  }
  if (tid < 8){
    float v = lcnt[tid];
    if (v != 0.f) atomicAdd(&gcnt[b*8 + tid], v);
  }
}

// ---------- patches = pooled @ proj_w + proj_b (k-split) ----------
__global__ __launch_bounds__(256) void k_patch(const float* __restrict__ gsums,
                        const float* __restrict__ gcnt,
                        const float* __restrict__ pw, const float* __restrict__ pb,
                        float* __restrict__ out){
  __shared__ float pool[8192];
  __shared__ float red[2048];
  int b = blockIdx.y, cx = blockIdx.x, tid = threadIdx.x;
  const float4* gs4 = (const float4*)(gsums + (size_t)b*8192);
  float4* pool4 = (float4*)pool;
  for (int e4=tid; e4<2048; e4+=256){
    int p = e4>>8;
    float inv = 1.f / fmaxf(gcnt[b*8 + p], 1.f);
    float4 v = gs4[e4];
    v.x*=inv; v.y*=inv; v.z*=inv; v.w*=inv;
    pool4[e4] = v;
  }
  __syncthreads();
  int c = tid & 31, ks = tid >> 5;
  int col = cx*32 + c;
  float acc[8] = {0,0,0,0,0,0,0,0};
  for (int k=ks*128; k<ks*128+128; ++k){
    float w = pw[(size_t)k*D_ + col];
    #pragma unroll
    for (int p=0;p<8;p++) acc[p] += pool[p*1024 + k]*w;
  }
  #pragma unroll
  for (int p=0;p<8;p++) red[tid*8 + p] = acc[p];
  __syncthreads();
  {
    int p = tid>>5, cc = tid&31;
    float s = 0.f;
    #pragma unroll
    for (int k2=0;k2<8;k2++) s += red[(k2*32 + cc)*8 + p];
    out[(size_t)(b*8+p)*D_ + cx*32 + cc] = s + pb[cx*32 + cc];
  }
}

// ---------- flags + first/last reduction + fused bounds (last block) ----------
__global__ void k_flagsb(const float* __restrict__ logit, const float* __restrict__ n2,
                        const float* __restrict__ dt, const float* __restrict__ b2p,
                        int* __restrict__ fl, float* __restrict__ ob){
  int g = blockIdx.x*256 + threadIdx.x;
  float b2 = b2p[0];
  int s = g & (S_-1);
  bool any = false;
  if (s >= 2){
    float z0 = logit[g] + b2;
    float z1 = logit[g-1] + b2;
    float z2 = logit[g-2] + b2;
    const float THR = 0.8472978603872037f;  // ln(0.7/0.3)
    bool run = (z0 > THR) & (z1 > THR) & (z2 > THR);
    float na = fmaxf(sqrtf(n2[g-1]), 1e-8f);
    float nb = fmaxf(sqrtf(n2[g]), 1e-8f);
    bool cosr = (dt[g-1] < 0.3f*na*nb) & (z0 > 0.f);
    any = run | cosr;
  }
  int mn = any ? s : 0x7FFFFFFF;
  int mx = any ? s : -1;
  #pragma unroll
  for (int off=32; off>0; off>>=1){
    mn = min(mn, __shfl_down(mn, off));
    mx = max(mx, __shfl_down(mx, off));
  }
  if ((threadIdx.x & 63) == 0){
    atomicMin(&fl[0], mn);
    atomicMax(&fl[1], mx);
  }
  __syncthreads();
  if (threadIdx.x == 0){
    __threadfence();
    int old = atomicAdd(&fl[2], 1);
    if (old == gridDim.x - 1){
      int f = atomicMin(&fl[0], 0x7FFFFFFF);
      int l = atomicMax(&fl[1], (int)0x80000000);
      if (l < 0){ ob[0] = -1.f; ob[1] = -1.f; }
      else {
        int st = f - 2; if (st < 0) st = 0;
        int en = l + 2; if (en > S_-1) en = S_-1;
        ob[0] = (float)st; ob[1] = (float)en;
      }
    }
  }
}

extern "C" void kernel_launch(void* const* d_in, const int* in_sizes, int n_in,
                              void* d_out, int out_size, void* d_ws, size_t ws_size,
                              hipStream_t stream){
  const float* latent = (const float*)d_in[0];
  const int*   mask   = (const int*)d_in[1];
  const float* proj_w = (const float*)d_in[2];
  const float* proj_b = (const float*)d_in[3];
  const float* eos_w1 = (const float*)d_in[4];
  const float* eos_b1 = (const float*)d_in[5];
  const float* eos_w2 = (const float*)d_in[6];
  const float* eos_b2 = (const float*)d_in[7];
  float* out = (float*)d_out;

  char* ws = (char*)d_ws;
  unsigned char* W1T8 = (unsigned char*)ws;              // 512 KB (1 MB reserved)
  unsigned char* X8   = (unsigned char*)(ws + 1048576);  // 32 MB
  float* fbase = (float*)(ws + 1048576 + 33554432);
  float* logit = fbase;                            // 32768
  float* norm2 = fbase + 32768;                    // 32768
  float* dotv  = fbase + 65536;                    // 32768
  float* gsums = fbase + 98304;                    // 65536
  float* gcnt  = fbase + 163840;                   // 64
  int* chunkbase = (int*)(fbase + 163904);         // 128 ints
  int* fl        = (int*)(fbase + 164032);         // 3 ints

  k_pre<<<1032, 256, 0, stream>>>(latent, norm2, dotv, X8, eos_w1, W1T8, mask,
                                  chunkbase, logit, gsums, gcnt, fl);
  k_pool<<<dim3(16,8), 256, 0, stream>>>(latent, mask, chunkbase, gsums, gcnt);
  k_patch<<<dim3(32,8), 256, 0, stream>>>(gsums, gcnt, proj_w, proj_b, out);
  k_mlp<<<1024, 256, 0, stream>>>(X8, W1T8, eos_b1, eos_w2, logit);
  k_flagsb<<<128, 256, 0, stream>>>(logit, norm2, dotv, eos_b2, fl, out + 65536);
}